// Round 13
// baseline (112.524 us; speedup 1.0000x reference)
//
#include <hip/hip_runtime.h>

// KANLayer: B=1024, I=64, O=64, H=32. ALL I/O float32 (per reference).
// out[b,o] = sum_i [ bw[o,i]*leaky(x[b,i]) + lw[o,i]*( sum_k W3[o,i,k]*h2[k] + b3[o,i] ) ]
//   h1[h] = leaky(x[b,i]*W1[o,i,h] + b1[o,i,h])
//   h2[k] = leaky(sum_h h1[h]*W2[o,i,k,h] + b2[o,i,k])
//
// R13: attack the per-iteration vmcnt(0) stall. All R5-R12 schedules landed
// 42-49us vs a ~10us issue floor: every iteration consumed ALL outstanding
// W2 loads at its top (1-deep prefetch) -> full drain -> per-wave stall of
// (latency - per-iter compute) every iteration, waves clump. Fix: 2-deep
// register pipeline (P0=consume, P1/P2 in flight; clamped prefetch index,
// no branch) so consumed data was requested ~480+ cyc earlier and 8 loads
// stay outstanding across the wait. ROWS=64/MT=4 (small pacc -> VGPR room,
// ~100 < 128 budget, the (256,4) never-spilled regime), i-slice 16/wave,
// grid 1024 blocks o-fastest = 4 blocks/CU = 4 waves/SIMD, LDS 34 KB.
// mfma_f32_16x16x32_f16, f32 accum, b2 folded into C, epilogue leaky via
// abs-modifier identity (leaky(v)*w = .505w*v + .495w*|v|).

#define H_   32
#define NI   64
#define NO   64
#define NB   1024
#define ROWS 64     // batch rows per block (4 m-tiles)
#define MT   4      // m-tiles per wave
#define XSTR 66     // x LDS row stride (uint pairs): 8B-aligned, 2-way banks (free)
#define NWAVE 4

typedef float    floatx4 __attribute__((ext_vector_type(4)));
typedef _Float16 halfx8  __attribute__((ext_vector_type(8)));
typedef _Float16 halfx2  __attribute__((ext_vector_type(2)));

union H8 { halfx8 v8; halfx2 v2[4]; unsigned int u[4]; };

__device__ inline float leaky(float v) { return fmaxf(v, 0.01f * v); }

__device__ inline unsigned int pkrtz(float a, float b) {   // (a,b) -> f16x2, RTZ
    return __builtin_bit_cast(unsigned int, __builtin_amdgcn_cvt_pkrtz(a, b));
}

__global__ __launch_bounds__(256, 4)
void kan_kernel(const float* __restrict__ x,  const float* __restrict__ W1,
                const float* __restrict__ b1, const float* __restrict__ W2,
                const float* __restrict__ b2, const float* __restrict__ W3,
                const float* __restrict__ b3, const float* __restrict__ lw,
                const float* __restrict__ bw, float* __restrict__ out)
{
    __shared__ unsigned int xsp[ROWS * XSTR];  // x dup-f16 pairs, 16.9 KB
    __shared__ _Float16 w1s[NI * H_];          // 4 KB
    __shared__ _Float16 b1s[NI * H_];          // 4 KB
    __shared__ unsigned int wbs[NI * H_];      // {lw*w3, b2} f16 pairs, 8 KB
    __shared__ float rc[ROWS];                 // 256 B
    __shared__ float part[NWAVE][ROWS];        // per-wave i-slice partials, 1 KB

    const int t    = threadIdx.x;
    const int o    = blockIdx.x;               // o fastest -> same-o blocks share XCD
    const int row0 = blockIdx.y * ROWS;

    // ---- stage x tile as duplicated f16 pairs (256 thr x 16 floats) ----
    const float* xsrc = x + (size_t)row0 * NI;
    #pragma unroll
    for (int v = 0; v < 4; ++v) {
        int fe = (v * 256 + t) * 4;            // multiple of 4
        int r = fe >> 6, c = fe & 63;
        float4 xv = *(const float4*)(xsrc + fe);
        uint2 lo = { pkrtz(xv.x, xv.x), pkrtz(xv.y, xv.y) };
        uint2 hi = { pkrtz(xv.z, xv.z), pkrtz(xv.w, xv.w) };
        *(uint2*)(&xsp[r * XSTR + c])     = lo;   // 66r+c even -> 8B aligned
        *(uint2*)(&xsp[r * XSTR + c + 2]) = hi;
    }
    // ---- stage W1/b1 for this o as f16 (2 passes of 4) ----
    const float* w1g = W1 + (size_t)o * NI * H_;
    const float* b1g = b1 + (size_t)o * NI * H_;
    #pragma unroll
    for (int v = 0; v < 2; ++v) {
        int e = (v * 256 + t) * 4;
        float4 a = *(const float4*)(w1g + e);
        float4 c = *(const float4*)(b1g + e);
        uint2 pa = { pkrtz(a.x, a.y), pkrtz(a.z, a.w) };
        uint2 pc = { pkrtz(c.x, c.y), pkrtz(c.z, c.w) };
        *(uint2*)(w1s + e) = pa;
        *(uint2*)(b1s + e) = pc;
    }
    // ---- stage {lw*w3, b2} pairs: 2048 entries, 8 per thread ----
    {
        int e = t * 8;                          // i = e>>5, k = e&31 .. +7
        float l = lw[o * NI + (e >> 5)];
        const float* w3g = W3 + (size_t)o * NI * H_ + e;
        const float* b2g = b2 + (size_t)o * NI * H_ + e;
        float4 wa = *(const float4*)(w3g), wb = *(const float4*)(w3g + 4);
        float4 ba = *(const float4*)(b2g), bb = *(const float4*)(b2g + 4);
        uint4 p0 = { pkrtz(l * wa.x, ba.x), pkrtz(l * wa.y, ba.y),
                     pkrtz(l * wa.z, ba.z), pkrtz(l * wa.w, ba.w) };
        uint4 p1 = { pkrtz(l * wb.x, bb.x), pkrtz(l * wb.y, bb.y),
                     pkrtz(l * wb.z, bb.z), pkrtz(l * wb.w, bb.w) };
        *(uint4*)(&wbs[e])     = p0;
        *(uint4*)(&wbs[e + 4]) = p1;
    }
    __syncthreads();

    const int lane = t & 63, wave = t >> 6;
    const int col  = lane & 15;            // MFMA n-index (h2 k-slot) / A m-offset
    const int kh   = lane >> 4;            // contraction quad
    const int koff = kh * 8;
    const int i0   = wave * 16;            // this wave's i-slice (16 wide)

    const float* w2p0 = W2 + ((size_t)(o * NI + i0) * H_ + col) * H_ + koff;
    const float* w2p1 = w2p0 + 16 * H_;
    const halfx2 slope = { (_Float16)0.01f, (_Float16)0.01f };

    floatx4 pacc[MT];
    #pragma unroll
    for (int m = 0; m < MT; ++m)
        pacc[m] = floatx4{0.f, 0.f, 0.f, 0.f};

    // ---- 2-deep register pipeline: P0 = consume, P1/P2 = in flight ----
    floatx4 A0, A1, A2, A3;   // P0
    floatx4 B0, B1, B2, B3;   // P1
    A0 = *(const floatx4*)(w2p0);
    A1 = *(const floatx4*)(w2p0 + 4);
    A2 = *(const floatx4*)(w2p1);
    A3 = *(const floatx4*)(w2p1 + 4);
    B0 = *(const floatx4*)(w2p0 + 1024);
    B1 = *(const floatx4*)(w2p0 + 1028);
    B2 = *(const floatx4*)(w2p1 + 1024);
    B3 = *(const floatx4*)(w2p1 + 1028);

    for (int ii = 0; ii < 16; ++ii) {
        const int i = i0 + ii;

        // issue loads 2 iterations ahead (clamped index: no branch)
        int ip = ii + 2; ip = (ip > 15) ? 15 : ip;
        const float* np0 = w2p0 + ip * 1024;
        const float* np1 = w2p1 + ip * 1024;
        floatx4 C0 = *(const floatx4*)(np0);
        floatx4 C1 = *(const floatx4*)(np0 + 4);
        floatx4 C2 = *(const floatx4*)(np1);
        floatx4 C3 = *(const floatx4*)(np1 + 4);

        // consume P0 (requested 2 iterations ago; P1/P2 stay outstanding)
        H8 bf0, bf1;
        bf0.u[0] = pkrtz(A0[0], A0[1]);  bf0.u[1] = pkrtz(A0[2], A0[3]);
        bf0.u[2] = pkrtz(A1[0], A1[1]);  bf0.u[3] = pkrtz(A1[2], A1[3]);
        bf1.u[0] = pkrtz(A2[0], A2[1]);  bf1.u[1] = pkrtz(A2[2], A2[3]);
        bf1.u[2] = pkrtz(A3[0], A3[1]);  bf1.u[3] = pkrtz(A3[2], A3[3]);

        H8 w1v, b1v;
        w1v.v8 = *(const halfx8*)(w1s + i * H_ + koff);
        b1v.v8 = *(const halfx8*)(b1s + i * H_ + koff);

        halfx2 q0 = __builtin_bit_cast(halfx2, wbs[i * H_ + col]);
        halfx2 q1 = __builtin_bit_cast(halfx2, wbs[i * H_ + col + 16]);
        float w3e0 = (float)q0[0], b2c0 = (float)q0[1];
        float w3e1 = (float)q1[0], b2c1 = (float)q1[1];
        float p0 = 0.505f * w3e0, nn0 = 0.495f * w3e0;  // leaky decomposition
        float p1 = 0.505f * w3e1, nn1 = 0.495f * w3e1;

        #pragma unroll
        for (int m = 0; m < MT; ++m) {
            halfx2 xx = __builtin_bit_cast(halfx2, xsp[(m * 16 + col) * XSTR + i]);
            H8 af;
            #pragma unroll
            for (int j = 0; j < 4; ++j) {
                halfx2 h = __builtin_elementwise_fma(xx, w1v.v2[j], b1v.v2[j]);
                af.v2[j] = __builtin_elementwise_max(h, h * slope);  // pk leaky
            }
            floatx4 c0 = { b2c0, b2c0, b2c0, b2c0 };   // b2 folded into C
            floatx4 c1 = { b2c1, b2c1, b2c1, b2c1 };
            c0 = __builtin_amdgcn_mfma_f32_16x16x32_f16(af.v8, bf0.v8, c0, 0, 0, 0);
            c1 = __builtin_amdgcn_mfma_f32_16x16x32_f16(af.v8, bf1.v8, c1, 0, 0, 0);
            // pacc += leaky(c)*w3e : leaky(v)*w = (.505w)*v + (.495w)*|v|
            #pragma unroll
            for (int r = 0; r < 4; ++r) {
                float acc = pacc[m][r];
                acc = fmaf(p0,  c0[r],
                      fmaf(nn0, fabsf(c0[r]),
                      fmaf(p1,  c1[r],
                      fmaf(nn1, fabsf(c1[r]), acc))));
                pacc[m][r] = acc;
            }
        }

        // rotate the pipeline
        A0 = B0; A1 = B1; A2 = B2; A3 = B3;
        B0 = C0; B1 = C1; B2 = C2; B3 = C3;
    }

    // ---- in-wave reduce over the 16 col lanes, deposit i-slice partials ----
    #pragma unroll
    for (int m = 0; m < MT; ++m) {
        #pragma unroll
        for (int r = 0; r < 4; ++r) {
            float v = pacc[m][r];
            v += __shfl_xor(v, 1, 64);
            v += __shfl_xor(v, 2, 64);
            v += __shfl_xor(v, 4, 64);
            v += __shfl_xor(v, 8, 64);
            if (col == 0)
                part[wave][m * 16 + kh * 4 + r] = v;   // C row = (lane>>4)*4+reg
        }
    }

    // ---- per-row constants (after main loop: no head-of-kernel serial lag)
    if (t < ROWS) {
        float s = 0.f;
        const float* bwp = bw + o * NI;
        const float* lp  = lw + o * NI;
        const float* b3p = b3 + o * NI;
        for (int i = 0; i < NI; ++i) {
            halfx2 hx = __builtin_bit_cast(halfx2, xsp[t * XSTR + i]);
            s += bwp[i] * leaky((float)hx[0]) + lp[i] * b3p[i];
        }
        rc[t] = s;
    }
    __syncthreads();

    // ---- cross-wave sum + per-row constant, write out[b,o] ----
    if (t < ROWS) {
        float v = rc[t];
        #pragma unroll
        for (int w = 0; w < NWAVE; ++w) v += part[w][t];
        out[(size_t)(row0 + t) * NO + o] = v;
    }
}

extern "C" void kernel_launch(void* const* d_in, const int* in_sizes, int n_in,
                              void* d_out, int out_size, void* d_ws, size_t ws_size,
                              hipStream_t stream) {
    const float* x  = (const float*)d_in[0];
    const float* W1 = (const float*)d_in[1];
    const float* b1 = (const float*)d_in[2];
    const float* W2 = (const float*)d_in[3];
    const float* b2 = (const float*)d_in[4];
    const float* W3 = (const float*)d_in[5];
    const float* b3 = (const float*)d_in[6];
    const float* lw = (const float*)d_in[7];
    const float* bw = (const float*)d_in[8];
    float* out = (float*)d_out;

    dim3 grid(NO, NB / ROWS);   // 1024 blocks, o fastest (XCD-local W2), 4/CU
    kan_kernel<<<grid, dim3(256), 0, stream>>>(x, W1, b1, W2, b2, W3, b3, lw, bw, out);
}